// Round 4
// baseline (692.071 us; speedup 1.0000x reference)
//
#include <hip/hip_runtime.h>
#include <hip/hip_bf16.h>

#define NN 2048
#define DD 384
#define BNROWS 16384       // 8*2048
#define KNNK 8
#define TWO_D 768
#define EPSV 1e-5f
#define SLOPE 0.2f
#define LDT 72   // padded LDS stride (bf16 elems)

typedef __attribute__((ext_vector_type(8))) short short8;
typedef __attribute__((ext_vector_type(4))) float f32x4;
typedef __hip_bfloat16 bf16;

// load element i of p as float, where p is fp32 (isf32=1) or bf16 (isf32=0)
__device__ __forceinline__ float ldf(const void* p, long i, int isf32) {
    return isf32 ? ((const float*)p)[i]
                 : __bfloat162float(((const bf16*)p)[i]);
}

__device__ __forceinline__ short f2b(float x) {
    bf16 h = __float2bfloat16(x);
    short s;
    __builtin_memcpy(&s, &h, 2);
    return s;
}

// ---- dtype detection ----
// flags[0]=x fp32?  flags[1]=bn fp32?  flags[2]=center fp32?  flags[3]=w1 fp32?  flags[4]=w2 fp32?
// Heuristic: scan first 2048 uint16 words; any exponent-field >= 134 (|v|>=128
// or NaN/Inf) is impossible for bf16 data drawn from N(0, sigma<=1), but near-
// certain among fp32 mantissa words (uniform bits).
__global__ void detect_flags(const void* x, const void* center, const void* w1,
                             const void* w2, const void* bng, int* flags) {
    __shared__ int sbad;
    int t = threadIdx.x;
    const unsigned short* p;
    if (blockIdx.x == 0)      p = (const unsigned short*)x;
    else if (blockIdx.x == 1) p = (const unsigned short*)center;
    else if (blockIdx.x == 2) p = (const unsigned short*)w1;
    else                      p = (const unsigned short*)w2;
    if (t == 0) sbad = 0;
    __syncthreads();
    int bad = 0;
    for (int i = t; i < 2048; i += 256) {
        unsigned e = (p[i] >> 7) & 0xFF;
        if (e >= 134) bad = 1;
    }
    if (bad) atomicOr(&sbad, 1);
    __syncthreads();
    if (t == 0) {
        int fi = (blockIdx.x == 0) ? 0 : (blockIdx.x == 1) ? 2 : (blockIdx.x == 2) ? 3 : 4;
        flags[fi] = sbad ? 1 : 0;
        if (blockIdx.x == 0)
            flags[1] = (((const unsigned*)bng)[0] == 0x3F800000u) ? 1 : 0;
    }
}

// ---- W_uv prep: rows 0..383 = w1a, rows 384..767 = w1b - w1a (bf16 out) ----
__global__ void prep_w(const void* __restrict__ w1, bf16* __restrict__ wuv,
                       const int* __restrict__ flags) {
    int f = flags[3];
    int t = blockIdx.x * 256 + threadIdx.x;
    if (t >= TWO_D * DD) return;
    int r = t / DD, c = t % DD;
    float o;
    if (r < DD) {
        o = ldf(w1, (long)r * TWO_D + c, f);
    } else {
        int rr = r - DD;
        o = ldf(w1, (long)rr * TWO_D + DD + c, f) - ldf(w1, (long)rr * TWO_D + c, f);
    }
    wuv[t] = __float2bfloat16(o);
}

// ---- w2 (384x384) -> bf16 ----
__global__ void conv_w2(const void* __restrict__ w2, bf16* __restrict__ w2b,
                        const int* __restrict__ flags) {
    int f = flags[4];
    int t = blockIdx.x * 256 + threadIdx.x;
    if (t >= DD * DD) return;
    w2b[t] = __float2bfloat16(ldf(w2, t, f));
}

// ---- KNN: top-8 by neg squared distance, tie -> smallest index ----
// Replicates numpy's left-to-right fp32 evaluation (no FMA contraction).
__global__ void knn_kernel(const void* __restrict__ center, int* __restrict__ idx_out,
                           const int* __restrict__ flags) {
#pragma clang fp contract(off)
    int f = flags[2];
    __shared__ float4 cs[256];
    int t = threadIdx.x;
    int q = blockIdx.x * 256 + t;
    int b = q >> 11;
    long cbase = (long)b * NN * 3;
    int n = q & (NN - 1);
    float qx = ldf(center, cbase + n * 3 + 0, f);
    float qy = ldf(center, cbase + n * 3 + 1, f);
    float qz = ldf(center, cbase + n * 3 + 2, f);
    float sqq = (qx * qx + qy * qy) + qz * qz;
    float best[KNNK]; int bidx[KNNK];
#pragma unroll
    for (int s = 0; s < KNNK; ++s) { best[s] = -INFINITY; bidx[s] = 0; }
    for (int tile = 0; tile < NN / 256; ++tile) {
        __syncthreads();
        int cj = tile * 256 + t;
        float cx = ldf(center, cbase + cj * 3 + 0, f);
        float cy = ldf(center, cbase + cj * 3 + 1, f);
        float cz = ldf(center, cbase + cj * 3 + 2, f);
        cs[t] = make_float4(cx, cy, cz, (cx * cx + cy * cy) + cz * cz);
        __syncthreads();
        for (int u = 0; u < 256; ++u) {
            float4 c4 = cs[u];
            float dot = (qx * c4.x + qy * c4.y) + qz * c4.z;
            float nd = (2.0f * dot - sqq) - c4.w;
            if (nd > best[KNNK - 1]) {
                float v = nd; int vi = tile * 256 + u;
#pragma unroll
                for (int s = 0; s < KNNK; ++s) {
                    if (nd > best[s]) {
                        float tb = best[s]; int ti = bidx[s];
                        best[s] = v; bidx[s] = vi;
                        v = tb; vi = ti;
                    }
                }
            }
        }
    }
#pragma unroll
    for (int s = 0; s < KNNK; ++s) idx_out[q * KNNK + s] = bidx[s];
}

// ---- MFMA bf16 GEMM: C[crow0+M x Nout] = A[arow0+M x K] * Bw[Nout x K]^T ----
// AFP: 1 = A dtype from flags[0] (fp32 converted during staging), 0 = A bf16.
// MODE 0: plain bf16 store. MODE 1: BN+leaky epilogue, out dtype per flags[0].
template<int BM, int BN, int MODE, int AFP>
__global__ __launch_bounds__(256) void gemm_bt(
    const void* __restrict__ A, const bf16* __restrict__ Bw,
    void* __restrict__ Cv, int Kdim, int Nout, int arow0, int crow0,
    const void* __restrict__ g2, const void* __restrict__ b2,
    const void* __restrict__ m2, const void* __restrict__ v2,
    const int* __restrict__ flags) {
    constexpr int TI = BM / 32, TJ = BN / 32;
    __shared__ __align__(16) short As[BM * LDT];
    __shared__ __align__(16) short Bs[BN * LDT];
    int fa = AFP ? flags[0] : 0;
    int tid = threadIdx.x;
    int bm0 = blockIdx.x * BM;
    int bn0 = blockIdx.y * BN;
    int w = tid >> 6, lane = tid & 63;
    int quad = lane >> 4, lr = lane & 15;
    int wm = (w & 1) * (BM / 2), wn = (w >> 1) * (BN / 2);
    f32x4 acc[TI][TJ] = {};
    for (int k0 = 0; k0 < Kdim; k0 += 64) {
        __syncthreads();
#pragma unroll
        for (int c = 0; c < BM / 32; ++c) {
            int ci = tid + c * 256;
            int row = ci >> 3, col = (ci & 7) * 8;
            if (AFP && fa) {
                const float* Af = (const float*)A;
                const float4* p = (const float4*)&Af[(size_t)(arow0 + bm0 + row) * Kdim + k0 + col];
                float4 f0 = p[0], f1 = p[1];
                short8 v;
                v[0] = f2b(f0.x); v[1] = f2b(f0.y); v[2] = f2b(f0.z); v[3] = f2b(f0.w);
                v[4] = f2b(f1.x); v[5] = f2b(f1.y); v[6] = f2b(f1.z); v[7] = f2b(f1.w);
                *reinterpret_cast<short8*>(&As[row * LDT + col]) = v;
            } else {
                const bf16* Ab = (const bf16*)A;
                *reinterpret_cast<int4*>(&As[row * LDT + col]) =
                    *reinterpret_cast<const int4*>(&Ab[(size_t)(arow0 + bm0 + row) * Kdim + k0 + col]);
            }
        }
#pragma unroll
        for (int c = 0; c < BN / 32; ++c) {
            int ci = tid + c * 256;
            int row = ci >> 3, col = (ci & 7) * 8;
            *reinterpret_cast<int4*>(&Bs[row * LDT + col]) =
                *reinterpret_cast<const int4*>(&Bw[(size_t)(bn0 + row) * Kdim + k0 + col]);
        }
        __syncthreads();
#pragma unroll
        for (int s = 0; s < 2; ++s) {
            short8 af[TI], bfr[TJ];
#pragma unroll
            for (int i = 0; i < TI; ++i)
                af[i] = *reinterpret_cast<const short8*>(&As[(wm + i * 16 + lr) * LDT + s * 32 + quad * 8]);
#pragma unroll
            for (int j = 0; j < TJ; ++j)
                bfr[j] = *reinterpret_cast<const short8*>(&Bs[(wn + j * 16 + lr) * LDT + s * 32 + quad * 8]);
#pragma unroll
            for (int i = 0; i < TI; ++i)
#pragma unroll
                for (int j = 0; j < TJ; ++j)
                    acc[i][j] = __builtin_amdgcn_mfma_f32_16x16x32_bf16(af[i], bfr[j], acc[i][j], 0, 0, 0);
        }
    }
    if (MODE == 0) {
        bf16* Cb = (bf16*)Cv;
#pragma unroll
        for (int i = 0; i < TI; ++i)
#pragma unroll
            for (int j = 0; j < TJ; ++j) {
                int col = bn0 + wn + j * 16 + lr;
#pragma unroll
                for (int r = 0; r < 4; ++r) {
                    int row = crow0 + bm0 + wm + i * 16 + quad * 4 + r;
                    Cb[(size_t)row * Nout + col] = __float2bfloat16(acc[i][j][r]);
                }
            }
    } else {
        int fb = flags[1];
        int fo = flags[0];   // output dtype follows x's dtype
#pragma unroll
        for (int j = 0; j < TJ; ++j) {
            int col = bn0 + wn + j * 16 + lr;
            float g  = ldf(g2, col, fb);
            float be = ldf(b2, col, fb);
            float mu = ldf(m2, col, fb);
            float va = ldf(v2, col, fb);
            float sc = g / sqrtf(va + EPSV);
            float sh = be - mu * sc;
#pragma unroll
            for (int i = 0; i < TI; ++i) {
#pragma unroll
                for (int r = 0; r < 4; ++r) {
                    int row = crow0 + bm0 + wm + i * 16 + quad * 4 + r;
                    float vvv = acc[i][j][r] * sc + sh;
                    vvv = vvv >= 0.f ? vvv : SLOPE * vvv;
                    if (fo) ((float*)Cv)[(size_t)row * Nout + col] = vvv;
                    else    ((bf16*)Cv)[(size_t)row * Nout + col] = __float2bfloat16(vvv);
                }
            }
        }
    }
}

// ---- gather neighbors + BN1 + leaky + max over k ----
__global__ void gather_max(const bf16* __restrict__ UV, const int* __restrict__ idx,
                           const void* __restrict__ g1, const void* __restrict__ b1,
                           const void* __restrict__ m1, const void* __restrict__ v1,
                           bf16* __restrict__ Mout, const int* __restrict__ flags) {
    int fb = flags[1];
    int d = threadIdx.x;                 // 0..383
    int row0 = blockIdx.x * 8;
    float g  = ldf(g1, d, fb);
    float be = ldf(b1, d, fb);
    float mu = ldf(m1, d, fb);
    float va = ldf(v1, d, fb);
    float sc = g / sqrtf(va + EPSV);
    float sh = be - mu * sc;
    for (int rr = 0; rr < 8; ++rr) {
        int q = row0 + rr;
        int base = q & ~(NN - 1);
        float vv = __bfloat162float(UV[(size_t)q * TWO_D + DD + d]);
        float acc = -INFINITY;
#pragma unroll
        for (int k = 0; k < KNNK; ++k) {
            int nb = idx[q * KNNK + k];
            float u = __bfloat162float(UV[(size_t)(base + nb) * TWO_D + d]);
            float h = (u + vv) * sc + sh;
            h = h >= 0.f ? h : SLOPE * h;
            acc = fmaxf(acc, h);
        }
        Mout[(size_t)q * DD + d] = __float2bfloat16(acc);
    }
}

extern "C" void kernel_launch(void* const* d_in, const int* in_sizes, int n_in,
                              void* d_out, int out_size, void* d_ws, size_t ws_size,
                              hipStream_t stream) {
    const void* x      = d_in[0];
    const void* center = d_in[1];
    const void* w1     = d_in[2];
    const void* w2v    = d_in[3];
    const void* bn1g   = d_in[4];
    const void* bn1b   = d_in[5];
    const void* bn1m   = d_in[6];
    const void* bn1v   = d_in[7];
    const void* bn2g   = d_in[8];
    const void* bn2b   = d_in[9];
    const void* bn2m   = d_in[10];
    const void* bn2v   = d_in[11];

    char* ws = (char*)d_ws;
    // Layout: idx [0, 0x80000) | wuv [0x80000, 0x110000) | flags [0x118000, +32)
    //         w2b [0x120000, +0x48000)
    int*  idx   = (int*)ws;
    bf16* wuv   = (bf16*)(ws + 0x80000);
    int*  flags = (int*)(ws + 0x118000);
    bf16* w2b   = (bf16*)(ws + 0x120000);

    detect_flags<<<dim3(4), dim3(256), 0, stream>>>(x, center, w1, w2v, bn1g, flags);
    prep_w<<<dim3((TWO_D * DD + 255) / 256), dim3(256), 0, stream>>>(w1, wuv, flags);
    conv_w2<<<dim3((DD * DD + 255) / 256), dim3(256), 0, stream>>>(w2v, w2b, flags);
    knn_kernel<<<dim3(BNROWS / 256), dim3(256), 0, stream>>>(center, idx, flags);

    if (ws_size >= (48u << 20)) {
        // ---- Path A: full problem; uses up to 44 MiB. ----
        bf16* UV = (bf16*)(ws + (8u << 20));       // 16384*768*2 = 24 MiB -> ends 32 MiB
        bf16* Mb = (bf16*)(ws + (32u << 20));      // 16384*384*2 = 12 MiB -> ends 44 MiB
        gemm_bt<128, 128, 0, 1><<<dim3(BNROWS / 128, TWO_D / 128), dim3(256), 0, stream>>>(
            x, wuv, UV, DD, TWO_D, 0, 0, nullptr, nullptr, nullptr, nullptr, flags);
        gather_max<<<dim3(BNROWS / 8), dim3(DD), 0, stream>>>(
            UV, idx, bn1g, bn1b, bn1m, bn1v, Mb, flags);
        gemm_bt<128, 128, 1, 0><<<dim3(BNROWS / 128, DD / 128), dim3(256), 0, stream>>>(
            Mb, w2b, d_out, DD, DD, 0, 0, bn2g, bn2b, bn2m, bn2v, flags);
    } else {
        // ---- Path B: per-batch; uses 6 MiB of ws. ----
        bf16* UVb = (bf16*)(ws + 0x180000);        // 2048*768*2 = 3 MiB
        bf16* Mbb = (bf16*)(ws + 0x480000);        // 2048*384*2 = 1.5 MiB -> ends 6 MiB
        for (int b = 0; b < 8; ++b) {
            gemm_bt<64, 64, 0, 1><<<dim3(NN / 64, TWO_D / 64), dim3(256), 0, stream>>>(
                x, wuv, UVb, DD, TWO_D, b * NN, 0, nullptr, nullptr, nullptr, nullptr, flags);
            gather_max<<<dim3(NN / 8), dim3(DD), 0, stream>>>(
                UVb, idx + (size_t)b * NN * KNNK, bn1g, bn1b, bn1m, bn1v, Mbb, flags);
            gemm_bt<64, 64, 1, 0><<<dim3(NN / 64, DD / 64), dim3(256), 0, stream>>>(
                Mbb, w2b, d_out, DD, DD, 0, b * NN, bn2g, bn2b, bn2m, bn2v, flags);
        }
    }
}

// Round 5
// 333.988 us; speedup vs baseline: 2.0721x; 2.0721x over previous
//
#include <hip/hip_runtime.h>
#include <hip/hip_bf16.h>

#define NN 2048
#define DD 384
#define BNROWS 16384       // 8*2048
#define KNNK 8
#define TWO_D 768
#define EPSV 1e-5f
#define SLOPE 0.2f
#define LDT 72   // padded LDS stride (bf16 elems)

typedef __attribute__((ext_vector_type(8))) short short8;
typedef __attribute__((ext_vector_type(4))) float f32x4;
typedef __hip_bfloat16 bf16;

// load element i of p as float, where p is fp32 (isf32=1) or bf16 (isf32=0)
__device__ __forceinline__ float ldf(const void* p, long i, int isf32) {
    return isf32 ? ((const float*)p)[i]
                 : __bfloat162float(((const bf16*)p)[i]);
}

__device__ __forceinline__ short f2b(float x) {
    bf16 h = __float2bfloat16(x);
    short s;
    __builtin_memcpy(&s, &h, 2);
    return s;
}

// ---- dtype detection ----
// flags[0]=x fp32?  flags[1]=bn fp32?  flags[2]=center fp32?  flags[3]=w1 fp32?  flags[4]=w2 fp32?
__global__ void detect_flags(const void* x, const void* center, const void* w1,
                             const void* w2, const void* bng, int* flags) {
    __shared__ int sbad;
    int t = threadIdx.x;
    const unsigned short* p;
    if (blockIdx.x == 0)      p = (const unsigned short*)x;
    else if (blockIdx.x == 1) p = (const unsigned short*)center;
    else if (blockIdx.x == 2) p = (const unsigned short*)w1;
    else                      p = (const unsigned short*)w2;
    if (t == 0) sbad = 0;
    __syncthreads();
    int bad = 0;
    for (int i = t; i < 2048; i += 256) {
        unsigned e = (p[i] >> 7) & 0xFF;
        if (e >= 134) bad = 1;   // impossible for N(0,1) bf16; near-certain for fp32 bits
    }
    if (bad) atomicOr(&sbad, 1);
    __syncthreads();
    if (t == 0) {
        int fi = (blockIdx.x == 0) ? 0 : (blockIdx.x == 1) ? 2 : (blockIdx.x == 2) ? 3 : 4;
        flags[fi] = sbad ? 1 : 0;
        if (blockIdx.x == 0)
            flags[1] = (((const unsigned*)bng)[0] == 0x3F800000u) ? 1 : 0;
    }
}

// ---- W_uv prep: rows 0..383 = w1a, rows 384..767 = w1b - w1a (bf16 out) ----
__global__ void prep_w(const void* __restrict__ w1, bf16* __restrict__ wuv,
                       const int* __restrict__ flags) {
    int f = flags[3];
    int t = blockIdx.x * 256 + threadIdx.x;
    if (t >= TWO_D * DD) return;
    int r = t / DD, c = t % DD;
    float o;
    if (r < DD) {
        o = ldf(w1, (long)r * TWO_D + c, f);
    } else {
        int rr = r - DD;
        o = ldf(w1, (long)rr * TWO_D + DD + c, f) - ldf(w1, (long)rr * TWO_D + c, f);
    }
    wuv[t] = __float2bfloat16(o);
}

// ---- w2 (384x384) -> bf16 ----
__global__ void conv_w2(const void* __restrict__ w2, bf16* __restrict__ w2b,
                        const int* __restrict__ flags) {
    int f = flags[4];
    int t = blockIdx.x * 256 + threadIdx.x;
    if (t >= DD * DD) return;
    w2b[t] = __float2bfloat16(ldf(w2, t, f));
}

// ---- KNN phase 1: per (query, candidate-chunk) top-8 ----
// grid (64 query-blocks, 8 chunks) x 256 thr. Writes indices transposed:
// cidx[(cc*8+s)*BNROWS + q]  (coalesced store & load).
__global__ void knn_p1(const void* __restrict__ center, int* __restrict__ cidx,
                       const int* __restrict__ flags) {
#pragma clang fp contract(off)
    int f = flags[2];
    __shared__ float4 cs[256];
    int t = threadIdx.x;
    int q = blockIdx.x * 256 + t;
    int cc = blockIdx.y;                 // candidate chunk 0..7
    int b = q >> 11;
    long cbase = (long)b * NN * 3;
    int n = q & (NN - 1);
    float qx = ldf(center, cbase + n * 3 + 0, f);
    float qy = ldf(center, cbase + n * 3 + 1, f);
    float qz = ldf(center, cbase + n * 3 + 2, f);
    float sqq = (qx * qx + qy * qy) + qz * qz;
    int cj = cc * 256 + t;
    {
        float cx = ldf(center, cbase + cj * 3 + 0, f);
        float cy = ldf(center, cbase + cj * 3 + 1, f);
        float cz = ldf(center, cbase + cj * 3 + 2, f);
        cs[t] = make_float4(cx, cy, cz, (cx * cx + cy * cy) + cz * cz);
    }
    __syncthreads();
    float best[KNNK]; int bidx[KNNK];
#pragma unroll
    for (int s = 0; s < KNNK; ++s) { best[s] = -INFINITY; bidx[s] = 0; }
    for (int u = 0; u < 256; ++u) {
        float4 c4 = cs[u];
        float dot = (qx * c4.x + qy * c4.y) + qz * c4.z;
        float nd = (2.0f * dot - sqq) - c4.w;
        if (nd > best[KNNK - 1]) {
            float v = nd; int vi = cc * 256 + u;
#pragma unroll
            for (int s = 0; s < KNNK; ++s) {
                if (nd > best[s]) {
                    float tb = best[s]; int ti = bidx[s];
                    best[s] = v; bidx[s] = vi;
                    v = tb; vi = ti;
                }
            }
        }
    }
#pragma unroll
    for (int s = 0; s < KNNK; ++s)
        cidx[(size_t)(cc * KNNK + s) * BNROWS + q] = bidx[s];
}

// ---- KNN phase 2: merge 8 chunks x 8, recomputing exact distances ----
// Scan order (chunk asc, rank desc-value) + strict-> insertion reproduces the
// single-pass global tie-break (ties -> smallest index).
__global__ void knn_p2(const void* __restrict__ center, const int* __restrict__ cidx,
                       int* __restrict__ idx_out, const int* __restrict__ flags) {
#pragma clang fp contract(off)
    int f = flags[2];
    int q = blockIdx.x * 256 + threadIdx.x;
    int b = q >> 11;
    long cbase = (long)b * NN * 3;
    int n = q & (NN - 1);
    float qx = ldf(center, cbase + n * 3 + 0, f);
    float qy = ldf(center, cbase + n * 3 + 1, f);
    float qz = ldf(center, cbase + n * 3 + 2, f);
    float sqq = (qx * qx + qy * qy) + qz * qz;
    float best[KNNK]; int bidx[KNNK];
#pragma unroll
    for (int s = 0; s < KNNK; ++s) { best[s] = -INFINITY; bidx[s] = 0; }
    for (int e = 0; e < 64; ++e) {
        int ci = cidx[(size_t)e * BNROWS + q];
        float cx = ldf(center, cbase + ci * 3 + 0, f);
        float cy = ldf(center, cbase + ci * 3 + 1, f);
        float cz = ldf(center, cbase + ci * 3 + 2, f);
        float cw = (cx * cx + cy * cy) + cz * cz;
        float dot = (qx * cx + qy * cy) + qz * cz;
        float nd = (2.0f * dot - sqq) - cw;
        if (nd > best[KNNK - 1]) {
            float v = nd; int vi = ci;
#pragma unroll
            for (int s = 0; s < KNNK; ++s) {
                if (nd > best[s]) {
                    float tb = best[s]; int ti = bidx[s];
                    best[s] = v; bidx[s] = vi;
                    v = tb; vi = ti;
                }
            }
        }
    }
#pragma unroll
    for (int s = 0; s < KNNK; ++s) idx_out[q * KNNK + s] = bidx[s];
}

// ---- MFMA bf16 GEMM: C[crow0+M x Nout] = A[arow0+M x K] * Bw[Nout x K]^T ----
// AFP: 1 = A dtype from flags[0] (fp32 converted during staging), 0 = A bf16.
// MODE 0: plain bf16 store. MODE 1: BN+leaky epilogue, out dtype per flags[0].
template<int BM, int BN, int MODE, int AFP>
__global__ __launch_bounds__(256) void gemm_bt(
    const void* __restrict__ A, const bf16* __restrict__ Bw,
    void* __restrict__ Cv, int Kdim, int Nout, int arow0, int crow0,
    const void* __restrict__ g2, const void* __restrict__ b2,
    const void* __restrict__ m2, const void* __restrict__ v2,
    const int* __restrict__ flags) {
    constexpr int TI = BM / 32, TJ = BN / 32;
    __shared__ __align__(16) short As[BM * LDT];
    __shared__ __align__(16) short Bs[BN * LDT];
    int fa = AFP ? flags[0] : 0;
    int tid = threadIdx.x;
    int bm0 = blockIdx.x * BM;
    int bn0 = blockIdx.y * BN;
    int w = tid >> 6, lane = tid & 63;
    int quad = lane >> 4, lr = lane & 15;
    int wm = (w & 1) * (BM / 2), wn = (w >> 1) * (BN / 2);
    f32x4 acc[TI][TJ] = {};
    for (int k0 = 0; k0 < Kdim; k0 += 64) {
        __syncthreads();
#pragma unroll
        for (int c = 0; c < BM / 32; ++c) {
            int ci = tid + c * 256;
            int row = ci >> 3, col = (ci & 7) * 8;
            if (AFP && fa) {
                const float* Af = (const float*)A;
                const float4* p = (const float4*)&Af[(size_t)(arow0 + bm0 + row) * Kdim + k0 + col];
                float4 f0 = p[0], f1 = p[1];
                short8 v;
                v[0] = f2b(f0.x); v[1] = f2b(f0.y); v[2] = f2b(f0.z); v[3] = f2b(f0.w);
                v[4] = f2b(f1.x); v[5] = f2b(f1.y); v[6] = f2b(f1.z); v[7] = f2b(f1.w);
                *reinterpret_cast<short8*>(&As[row * LDT + col]) = v;
            } else {
                const bf16* Ab = (const bf16*)A;
                *reinterpret_cast<int4*>(&As[row * LDT + col]) =
                    *reinterpret_cast<const int4*>(&Ab[(size_t)(arow0 + bm0 + row) * Kdim + k0 + col]);
            }
        }
#pragma unroll
        for (int c = 0; c < BN / 32; ++c) {
            int ci = tid + c * 256;
            int row = ci >> 3, col = (ci & 7) * 8;
            *reinterpret_cast<int4*>(&Bs[row * LDT + col]) =
                *reinterpret_cast<const int4*>(&Bw[(size_t)(bn0 + row) * Kdim + k0 + col]);
        }
        __syncthreads();
#pragma unroll
        for (int s = 0; s < 2; ++s) {
            short8 af[TI], bfr[TJ];
#pragma unroll
            for (int i = 0; i < TI; ++i)
                af[i] = *reinterpret_cast<const short8*>(&As[(wm + i * 16 + lr) * LDT + s * 32 + quad * 8]);
#pragma unroll
            for (int j = 0; j < TJ; ++j)
                bfr[j] = *reinterpret_cast<const short8*>(&Bs[(wn + j * 16 + lr) * LDT + s * 32 + quad * 8]);
#pragma unroll
            for (int i = 0; i < TI; ++i)
#pragma unroll
                for (int j = 0; j < TJ; ++j)
                    acc[i][j] = __builtin_amdgcn_mfma_f32_16x16x32_bf16(af[i], bfr[j], acc[i][j], 0, 0, 0);
        }
    }
    if (MODE == 0) {
        bf16* Cb = (bf16*)Cv;
#pragma unroll
        for (int i = 0; i < TI; ++i)
#pragma unroll
            for (int j = 0; j < TJ; ++j) {
                int col = bn0 + wn + j * 16 + lr;
#pragma unroll
                for (int r = 0; r < 4; ++r) {
                    int row = crow0 + bm0 + wm + i * 16 + quad * 4 + r;
                    Cb[(size_t)row * Nout + col] = __float2bfloat16(acc[i][j][r]);
                }
            }
    } else {
        int fb = flags[1];
        int fo = flags[0];   // output dtype follows x's dtype
#pragma unroll
        for (int j = 0; j < TJ; ++j) {
            int col = bn0 + wn + j * 16 + lr;
            float g  = ldf(g2, col, fb);
            float be = ldf(b2, col, fb);
            float mu = ldf(m2, col, fb);
            float va = ldf(v2, col, fb);
            float sc = g / sqrtf(va + EPSV);
            float sh = be - mu * sc;
#pragma unroll
            for (int i = 0; i < TI; ++i) {
#pragma unroll
                for (int r = 0; r < 4; ++r) {
                    int row = crow0 + bm0 + wm + i * 16 + quad * 4 + r;
                    float vvv = acc[i][j][r] * sc + sh;
                    vvv = vvv >= 0.f ? vvv : SLOPE * vvv;
                    if (fo) ((float*)Cv)[(size_t)row * Nout + col] = vvv;
                    else    ((bf16*)Cv)[(size_t)row * Nout + col] = __float2bfloat16(vvv);
                }
            }
        }
    }
}

// ---- gather neighbors + BN1 + leaky + max over k ----
__global__ void gather_max(const bf16* __restrict__ UV, const int* __restrict__ idx,
                           const void* __restrict__ g1, const void* __restrict__ b1,
                           const void* __restrict__ m1, const void* __restrict__ v1,
                           bf16* __restrict__ Mout, const int* __restrict__ flags) {
    int fb = flags[1];
    int d = threadIdx.x;                 // 0..383
    int row0 = blockIdx.x * 8;
    float g  = ldf(g1, d, fb);
    float be = ldf(b1, d, fb);
    float mu = ldf(m1, d, fb);
    float va = ldf(v1, d, fb);
    float sc = g / sqrtf(va + EPSV);
    float sh = be - mu * sc;
    for (int rr = 0; rr < 8; ++rr) {
        int q = row0 + rr;
        int base = q & ~(NN - 1);
        float vv = __bfloat162float(UV[(size_t)q * TWO_D + DD + d]);
        float acc = -INFINITY;
#pragma unroll
        for (int k = 0; k < KNNK; ++k) {
            int nb = idx[q * KNNK + k];
            float u = __bfloat162float(UV[(size_t)(base + nb) * TWO_D + d]);
            float h = (u + vv) * sc + sh;
            h = h >= 0.f ? h : SLOPE * h;
            acc = fmaxf(acc, h);
        }
        Mout[(size_t)q * DD + d] = __float2bfloat16(acc);
    }
}

extern "C" void kernel_launch(void* const* d_in, const int* in_sizes, int n_in,
                              void* d_out, int out_size, void* d_ws, size_t ws_size,
                              hipStream_t stream) {
    const void* x      = d_in[0];
    const void* center = d_in[1];
    const void* w1     = d_in[2];
    const void* w2v    = d_in[3];
    const void* bn1g   = d_in[4];
    const void* bn1b   = d_in[5];
    const void* bn1m   = d_in[6];
    const void* bn1v   = d_in[7];
    const void* bn2g   = d_in[8];
    const void* bn2b   = d_in[9];
    const void* bn2m   = d_in[10];
    const void* bn2v   = d_in[11];

    char* ws = (char*)d_ws;
    // Layout: idx [0, 0x80000) | wuv [0x80000, 0x110000) | flags [0x118000, +32)
    //         w2b [0x120000, +0x48000) | cidx [0x180000, +4 MiB) (transient:
    //         dead after knn_p2, safely overlapped by path-B UVb later)
    int*  idx   = (int*)ws;
    bf16* wuv   = (bf16*)(ws + 0x80000);
    int*  flags = (int*)(ws + 0x118000);
    bf16* w2b   = (bf16*)(ws + 0x120000);
    int*  cidx  = (int*)(ws + 0x180000);

    detect_flags<<<dim3(4), dim3(256), 0, stream>>>(x, center, w1, w2v, bn1g, flags);
    prep_w<<<dim3((TWO_D * DD + 255) / 256), dim3(256), 0, stream>>>(w1, wuv, flags);
    conv_w2<<<dim3((DD * DD + 255) / 256), dim3(256), 0, stream>>>(w2v, w2b, flags);
    knn_p1<<<dim3(BNROWS / 256, 8), dim3(256), 0, stream>>>(center, cidx, flags);
    knn_p2<<<dim3(BNROWS / 256), dim3(256), 0, stream>>>(center, cidx, idx, flags);

    if (ws_size >= (48u << 20)) {
        // ---- Path A: full problem; uses up to 44 MiB. ----
        bf16* UV = (bf16*)(ws + (8u << 20));       // 16384*768*2 = 24 MiB -> ends 32 MiB
        bf16* Mb = (bf16*)(ws + (32u << 20));      // 16384*384*2 = 12 MiB -> ends 44 MiB
        gemm_bt<128, 128, 0, 1><<<dim3(BNROWS / 128, TWO_D / 128), dim3(256), 0, stream>>>(
            x, wuv, UV, DD, TWO_D, 0, 0, nullptr, nullptr, nullptr, nullptr, flags);
        gather_max<<<dim3(BNROWS / 8), dim3(DD), 0, stream>>>(
            UV, idx, bn1g, bn1b, bn1m, bn1v, Mb, flags);
        gemm_bt<128, 128, 1, 0><<<dim3(BNROWS / 128, DD / 128), dim3(256), 0, stream>>>(
            Mb, w2b, d_out, DD, DD, 0, 0, bn2g, bn2b, bn2m, bn2v, flags);
    } else {
        // ---- Path B: per-batch; uses 6 MiB of ws. ----
        bf16* UVb = (bf16*)(ws + 0x180000);        // 2048*768*2 = 3 MiB
        bf16* Mbb = (bf16*)(ws + 0x480000);        // 2048*384*2 = 1.5 MiB -> ends 6 MiB
        for (int b = 0; b < 8; ++b) {
            gemm_bt<64, 64, 0, 1><<<dim3(NN / 64, TWO_D / 64), dim3(256), 0, stream>>>(
                x, wuv, UVb, DD, TWO_D, b * NN, 0, nullptr, nullptr, nullptr, nullptr, flags);
            gather_max<<<dim3(NN / 8), dim3(DD), 0, stream>>>(
                UVb, idx + (size_t)b * NN * KNNK, bn1g, bn1b, bn1m, bn1v, Mbb, flags);
            gemm_bt<64, 64, 1, 0><<<dim3(NN / 64, DD / 64), dim3(256), 0, stream>>>(
                Mbb, w2b, d_out, DD, DD, 0, b * NN, bn2g, bn2b, bn2m, bn2v, flags);
        }
    }
}

// Round 6
// 230.066 us; speedup vs baseline: 3.0081x; 1.4517x over previous
//
#include <hip/hip_runtime.h>
#include <hip/hip_bf16.h>

#define NN 2048
#define DD 384
#define BNROWS 16384       // 8*2048
#define KNNK 8
#define TWO_D 768
#define EPSV 1e-5f
#define SLOPE 0.2f
#define LDT 72   // padded LDS stride (bf16 elems)

typedef __attribute__((ext_vector_type(8))) short short8;
typedef __attribute__((ext_vector_type(4))) float f32x4;
typedef __hip_bfloat16 bf16;

// load element i of p as float, where p is fp32 (isf32=1) or bf16 (isf32=0)
__device__ __forceinline__ float ldf(const void* p, long i, int isf32) {
    return isf32 ? ((const float*)p)[i]
                 : __bfloat162float(((const bf16*)p)[i]);
}

__device__ __forceinline__ short f2b(float x) {
    bf16 h = __float2bfloat16(x);
    short s;
    __builtin_memcpy(&s, &h, 2);
    return s;
}

// Branch-free sorted top-8 insert (desc values; strict > => ties keep earlier
// entry above, i.e. smallest index wins). Bottom-up so old values are used.
#define LADDER(nd, ci) { \
    bool c0 = (nd) > b0, c1 = (nd) > b1, c2 = (nd) > b2, c3 = (nd) > b3; \
    bool c4 = (nd) > b4, c5 = (nd) > b5, c6 = (nd) > b6, c7 = (nd) > b7; \
    b7 = c6 ? b6 : (c7 ? (nd) : b7); i7 = c6 ? i6 : (c7 ? (ci) : i7); \
    b6 = c5 ? b5 : (c6 ? (nd) : b6); i6 = c5 ? i5 : (c6 ? (ci) : i6); \
    b5 = c4 ? b4 : (c5 ? (nd) : b5); i5 = c4 ? i4 : (c5 ? (ci) : i5); \
    b4 = c3 ? b3 : (c4 ? (nd) : b4); i4 = c3 ? i3 : (c4 ? (ci) : i4); \
    b3 = c2 ? b2 : (c3 ? (nd) : b3); i3 = c2 ? i2 : (c3 ? (ci) : i3); \
    b2 = c1 ? b1 : (c2 ? (nd) : b2); i2 = c1 ? i1 : (c2 ? (ci) : i2); \
    b1 = c0 ? b0 : (c1 ? (nd) : b1); i1 = c0 ? i0 : (c1 ? (ci) : i1); \
    b0 = c0 ? (nd) : b0;             i0 = c0 ? (ci) : i0; \
}

// ---- dtype detection ----
// flags[0]=x fp32?  flags[1]=bn fp32?  flags[2]=center fp32?  flags[3]=w1 fp32?  flags[4]=w2 fp32?
__global__ void detect_flags(const void* x, const void* center, const void* w1,
                             const void* w2, const void* bng, int* flags) {
    __shared__ int sbad;
    int t = threadIdx.x;
    const unsigned short* p;
    if (blockIdx.x == 0)      p = (const unsigned short*)x;
    else if (blockIdx.x == 1) p = (const unsigned short*)center;
    else if (blockIdx.x == 2) p = (const unsigned short*)w1;
    else                      p = (const unsigned short*)w2;
    if (t == 0) sbad = 0;
    __syncthreads();
    int bad = 0;
    for (int i = t; i < 2048; i += 256) {
        unsigned e = (p[i] >> 7) & 0xFF;
        if (e >= 134) bad = 1;   // impossible for N(0,1) bf16; near-certain for fp32 bits
    }
    if (bad) atomicOr(&sbad, 1);
    __syncthreads();
    if (t == 0) {
        int fi = (blockIdx.x == 0) ? 0 : (blockIdx.x == 1) ? 2 : (blockIdx.x == 2) ? 3 : 4;
        flags[fi] = sbad ? 1 : 0;
        if (blockIdx.x == 0)
            flags[1] = (((const unsigned*)bng)[0] == 0x3F800000u) ? 1 : 0;
    }
}

// ---- W_uv prep: rows 0..383 = w1a, rows 384..767 = w1b - w1a (bf16 out) ----
__global__ void prep_w(const void* __restrict__ w1, bf16* __restrict__ wuv,
                       const int* __restrict__ flags) {
    int f = flags[3];
    int t = blockIdx.x * 256 + threadIdx.x;
    if (t >= TWO_D * DD) return;
    int r = t / DD, c = t % DD;
    float o;
    if (r < DD) {
        o = ldf(w1, (long)r * TWO_D + c, f);
    } else {
        int rr = r - DD;
        o = ldf(w1, (long)rr * TWO_D + DD + c, f) - ldf(w1, (long)rr * TWO_D + c, f);
    }
    wuv[t] = __float2bfloat16(o);
}

// ---- w2 (384x384) -> bf16 ----
__global__ void conv_w2(const void* __restrict__ w2, bf16* __restrict__ w2b,
                        const int* __restrict__ flags) {
    int f = flags[4];
    int t = blockIdx.x * 256 + threadIdx.x;
    if (t >= DD * DD) return;
    w2b[t] = __float2bfloat16(ldf(w2, t, f));
}

// ---- KNN phase 1: per (query, candidate-chunk-of-256) top-8, scalar ladder --
// grid (64 query-blocks, 8 chunks) x 256 thr. Indices written transposed.
__global__ void knn_p1(const void* __restrict__ center, int* __restrict__ cidx,
                       const int* __restrict__ flags) {
#pragma clang fp contract(off)
    int f = flags[2];
    __shared__ float4 cs[256];
    int t = threadIdx.x;
    int q = blockIdx.x * 256 + t;
    int cc = blockIdx.y;                 // candidate chunk 0..7
    int b = q >> 11;
    long cbase = (long)b * NN * 3;
    int n = q & (NN - 1);
    float qx = ldf(center, cbase + n * 3 + 0, f);
    float qy = ldf(center, cbase + n * 3 + 1, f);
    float qz = ldf(center, cbase + n * 3 + 2, f);
    float sqq = (qx * qx + qy * qy) + qz * qz;
    {
        int cj = cc * 256 + t;
        float cx = ldf(center, cbase + cj * 3 + 0, f);
        float cy = ldf(center, cbase + cj * 3 + 1, f);
        float cz = ldf(center, cbase + cj * 3 + 2, f);
        cs[t] = make_float4(cx, cy, cz, (cx * cx + cy * cy) + cz * cz);
    }
    __syncthreads();
    float b0 = -INFINITY, b1 = -INFINITY, b2 = -INFINITY, b3 = -INFINITY;
    float b4 = -INFINITY, b5 = -INFINITY, b6 = -INFINITY, b7 = -INFINITY;
    int i0 = 0, i1 = 0, i2 = 0, i3 = 0, i4 = 0, i5 = 0, i6 = 0, i7 = 0;
    int cbase2 = cc * 256;
    for (int u = 0; u < 256; ++u) {
        float4 c4v = cs[u];
        float dot = (qx * c4v.x + qy * c4v.y) + qz * c4v.z;
        float nd = (2.0f * dot - sqq) - c4v.w;
        int ci = cbase2 + u;
        LADDER(nd, ci);
    }
    size_t o = (size_t)(cc * KNNK) * BNROWS + q;
    cidx[o + 0 * BNROWS] = i0; cidx[o + 1 * BNROWS] = i1;
    cidx[o + 2 * BNROWS] = i2; cidx[o + 3 * BNROWS] = i3;
    cidx[o + 4 * BNROWS] = i4; cidx[o + 5 * BNROWS] = i5;
    cidx[o + 6 * BNROWS] = i6; cidx[o + 7 * BNROWS] = i7;
}

// ---- KNN phase 2: merge 8 chunks x 8, recomputing exact distances ----
// Scan order (chunk asc, rank within chunk) + strict-> ladder reproduces the
// global tie-break (ties -> smallest index).
__global__ void knn_p2(const void* __restrict__ center, const int* __restrict__ cidx,
                       int* __restrict__ idx_out, const int* __restrict__ flags) {
#pragma clang fp contract(off)
    int f = flags[2];
    int q = blockIdx.x * 64 + threadIdx.x;
    int b = q >> 11;
    long cbase = (long)b * NN * 3;
    int n = q & (NN - 1);
    float qx = ldf(center, cbase + n * 3 + 0, f);
    float qy = ldf(center, cbase + n * 3 + 1, f);
    float qz = ldf(center, cbase + n * 3 + 2, f);
    float sqq = (qx * qx + qy * qy) + qz * qz;
    float b0 = -INFINITY, b1 = -INFINITY, b2 = -INFINITY, b3 = -INFINITY;
    float b4 = -INFINITY, b5 = -INFINITY, b6 = -INFINITY, b7 = -INFINITY;
    int i0 = 0, i1 = 0, i2 = 0, i3 = 0, i4 = 0, i5 = 0, i6 = 0, i7 = 0;
    for (int e = 0; e < 64; ++e) {
        int ci = cidx[(size_t)e * BNROWS + q];
        float cx = ldf(center, cbase + ci * 3 + 0, f);
        float cy = ldf(center, cbase + ci * 3 + 1, f);
        float cz = ldf(center, cbase + ci * 3 + 2, f);
        float cw = (cx * cx + cy * cy) + cz * cz;
        float dot = (qx * cx + qy * cy) + qz * cz;
        float nd = (2.0f * dot - sqq) - cw;
        LADDER(nd, ci);
    }
    idx_out[q * KNNK + 0] = i0; idx_out[q * KNNK + 1] = i1;
    idx_out[q * KNNK + 2] = i2; idx_out[q * KNNK + 3] = i3;
    idx_out[q * KNNK + 4] = i4; idx_out[q * KNNK + 5] = i5;
    idx_out[q * KNNK + 6] = i6; idx_out[q * KNNK + 7] = i7;
}

// ---- MFMA bf16 GEMM: C[crow0+M x Nout] = A[arow0+M x K] * Bw[Nout x K]^T ----
// AFP: 1 = A dtype from flags[0] (fp32 converted during staging), 0 = A bf16.
// MODE 0: plain bf16 store. MODE 1: BN+leaky epilogue, out dtype per flags[0].
template<int BM, int BN, int MODE, int AFP>
__global__ __launch_bounds__(256) void gemm_bt(
    const void* __restrict__ A, const bf16* __restrict__ Bw,
    void* __restrict__ Cv, int Kdim, int Nout, int arow0, int crow0,
    const void* __restrict__ g2, const void* __restrict__ b2,
    const void* __restrict__ m2, const void* __restrict__ v2,
    const int* __restrict__ flags) {
    constexpr int TI = BM / 32, TJ = BN / 32;
    __shared__ __align__(16) short As[BM * LDT];
    __shared__ __align__(16) short Bs[BN * LDT];
    int fa = AFP ? flags[0] : 0;
    int tid = threadIdx.x;
    int bm0 = blockIdx.x * BM;
    int bn0 = blockIdx.y * BN;
    int w = tid >> 6, lane = tid & 63;
    int quad = lane >> 4, lr = lane & 15;
    int wm = (w & 1) * (BM / 2), wn = (w >> 1) * (BN / 2);
    f32x4 acc[TI][TJ] = {};
    for (int k0 = 0; k0 < Kdim; k0 += 64) {
        __syncthreads();
#pragma unroll
        for (int c = 0; c < BM / 32; ++c) {
            int ci = tid + c * 256;
            int row = ci >> 3, col = (ci & 7) * 8;
            if (AFP && fa) {
                const float* Af = (const float*)A;
                const float4* p = (const float4*)&Af[(size_t)(arow0 + bm0 + row) * Kdim + k0 + col];
                float4 f0 = p[0], f1 = p[1];
                short8 v;
                v[0] = f2b(f0.x); v[1] = f2b(f0.y); v[2] = f2b(f0.z); v[3] = f2b(f0.w);
                v[4] = f2b(f1.x); v[5] = f2b(f1.y); v[6] = f2b(f1.z); v[7] = f2b(f1.w);
                *reinterpret_cast<short8*>(&As[row * LDT + col]) = v;
            } else {
                const bf16* Ab = (const bf16*)A;
                *reinterpret_cast<int4*>(&As[row * LDT + col]) =
                    *reinterpret_cast<const int4*>(&Ab[(size_t)(arow0 + bm0 + row) * Kdim + k0 + col]);
            }
        }
#pragma unroll
        for (int c = 0; c < BN / 32; ++c) {
            int ci = tid + c * 256;
            int row = ci >> 3, col = (ci & 7) * 8;
            *reinterpret_cast<int4*>(&Bs[row * LDT + col]) =
                *reinterpret_cast<const int4*>(&Bw[(size_t)(bn0 + row) * Kdim + k0 + col]);
        }
        __syncthreads();
#pragma unroll
        for (int s = 0; s < 2; ++s) {
            short8 af[TI], bfr[TJ];
#pragma unroll
            for (int i = 0; i < TI; ++i)
                af[i] = *reinterpret_cast<const short8*>(&As[(wm + i * 16 + lr) * LDT + s * 32 + quad * 8]);
#pragma unroll
            for (int j = 0; j < TJ; ++j)
                bfr[j] = *reinterpret_cast<const short8*>(&Bs[(wn + j * 16 + lr) * LDT + s * 32 + quad * 8]);
#pragma unroll
            for (int i = 0; i < TI; ++i)
#pragma unroll
                for (int j = 0; j < TJ; ++j)
                    acc[i][j] = __builtin_amdgcn_mfma_f32_16x16x32_bf16(af[i], bfr[j], acc[i][j], 0, 0, 0);
        }
    }
    if (MODE == 0) {
        bf16* Cb = (bf16*)Cv;
#pragma unroll
        for (int i = 0; i < TI; ++i)
#pragma unroll
            for (int j = 0; j < TJ; ++j) {
                int col = bn0 + wn + j * 16 + lr;
#pragma unroll
                for (int r = 0; r < 4; ++r) {
                    int row = crow0 + bm0 + wm + i * 16 + quad * 4 + r;
                    Cb[(size_t)row * Nout + col] = __float2bfloat16(acc[i][j][r]);
                }
            }
    } else {
        int fb = flags[1];
        int fo = flags[0];   // output dtype follows x's dtype
#pragma unroll
        for (int j = 0; j < TJ; ++j) {
            int col = bn0 + wn + j * 16 + lr;
            float g  = ldf(g2, col, fb);
            float be = ldf(b2, col, fb);
            float mu = ldf(m2, col, fb);
            float va = ldf(v2, col, fb);
            float sc = g / sqrtf(va + EPSV);
            float sh = be - mu * sc;
#pragma unroll
            for (int i = 0; i < TI; ++i) {
#pragma unroll
                for (int r = 0; r < 4; ++r) {
                    int row = crow0 + bm0 + wm + i * 16 + quad * 4 + r;
                    float vvv = acc[i][j][r] * sc + sh;
                    vvv = vvv >= 0.f ? vvv : SLOPE * vvv;
                    if (fo) ((float*)Cv)[(size_t)row * Nout + col] = vvv;
                    else    ((bf16*)Cv)[(size_t)row * Nout + col] = __float2bfloat16(vvv);
                }
            }
        }
    }
}

// ---- gather neighbors + BN1 + leaky + max over k ----
__global__ void gather_max(const bf16* __restrict__ UV, const int* __restrict__ idx,
                           const void* __restrict__ g1, const void* __restrict__ b1,
                           const void* __restrict__ m1, const void* __restrict__ v1,
                           bf16* __restrict__ Mout, const int* __restrict__ flags) {
    int fb = flags[1];
    int d = threadIdx.x;                 // 0..383
    int row0 = blockIdx.x * 8;
    float g  = ldf(g1, d, fb);
    float be = ldf(b1, d, fb);
    float mu = ldf(m1, d, fb);
    float va = ldf(v1, d, fb);
    float sc = g / sqrtf(va + EPSV);
    float sh = be - mu * sc;
    for (int rr = 0; rr < 8; ++rr) {
        int q = row0 + rr;
        int base = q & ~(NN - 1);
        float vv = __bfloat162float(UV[(size_t)q * TWO_D + DD + d]);
        float acc = -INFINITY;
#pragma unroll
        for (int k = 0; k < KNNK; ++k) {
            int nb = idx[q * KNNK + k];
            float u = __bfloat162float(UV[(size_t)(base + nb) * TWO_D + d]);
            float h = (u + vv) * sc + sh;
            h = h >= 0.f ? h : SLOPE * h;
            acc = fmaxf(acc, h);
        }
        Mout[(size_t)q * DD + d] = __float2bfloat16(acc);
    }
}

extern "C" void kernel_launch(void* const* d_in, const int* in_sizes, int n_in,
                              void* d_out, int out_size, void* d_ws, size_t ws_size,
                              hipStream_t stream) {
    const void* x      = d_in[0];
    const void* center = d_in[1];
    const void* w1     = d_in[2];
    const void* w2v    = d_in[3];
    const void* bn1g   = d_in[4];
    const void* bn1b   = d_in[5];
    const void* bn1m   = d_in[6];
    const void* bn1v   = d_in[7];
    const void* bn2g   = d_in[8];
    const void* bn2b   = d_in[9];
    const void* bn2m   = d_in[10];
    const void* bn2v   = d_in[11];

    char* ws = (char*)d_ws;
    // Layout: idx [0, 0x80000) | wuv [0x80000, 0x110000) | flags [0x118000, +32)
    //         w2b [0x120000, +0x48000) | cidx [0x180000, +4 MiB) (transient:
    //         dead after knn_p2, safely overlapped by path-B UVb later)
    int*  idx   = (int*)ws;
    bf16* wuv   = (bf16*)(ws + 0x80000);
    int*  flags = (int*)(ws + 0x118000);
    bf16* w2b   = (bf16*)(ws + 0x120000);
    int*  cidx  = (int*)(ws + 0x180000);

    detect_flags<<<dim3(4), dim3(256), 0, stream>>>(x, center, w1, w2v, bn1g, flags);
    prep_w<<<dim3((TWO_D * DD + 255) / 256), dim3(256), 0, stream>>>(w1, wuv, flags);
    conv_w2<<<dim3((DD * DD + 255) / 256), dim3(256), 0, stream>>>(w2v, w2b, flags);
    knn_p1<<<dim3(BNROWS / 256, 8), dim3(256), 0, stream>>>(center, cidx, flags);
    knn_p2<<<dim3(BNROWS / 64), dim3(64), 0, stream>>>(center, cidx, idx, flags);

    if (ws_size >= (48u << 20)) {
        // ---- Path A: full problem; uses up to 44 MiB. ----
        bf16* UV = (bf16*)(ws + (8u << 20));       // 16384*768*2 = 24 MiB -> ends 32 MiB
        bf16* Mb = (bf16*)(ws + (32u << 20));      // 16384*384*2 = 12 MiB -> ends 44 MiB
        gemm_bt<128, 128, 0, 1><<<dim3(BNROWS / 128, TWO_D / 128), dim3(256), 0, stream>>>(
            x, wuv, UV, DD, TWO_D, 0, 0, nullptr, nullptr, nullptr, nullptr, flags);
        gather_max<<<dim3(BNROWS / 8), dim3(DD), 0, stream>>>(
            UV, idx, bn1g, bn1b, bn1m, bn1v, Mb, flags);
        gemm_bt<128, 128, 1, 0><<<dim3(BNROWS / 128, DD / 128), dim3(256), 0, stream>>>(
            Mb, w2b, d_out, DD, DD, 0, 0, bn2g, bn2b, bn2m, bn2v, flags);
    } else {
        // ---- Path B: per-batch; uses 6 MiB of ws. ----
        bf16* UVb = (bf16*)(ws + 0x180000);        // 2048*768*2 = 3 MiB
        bf16* Mbb = (bf16*)(ws + 0x480000);        // 2048*384*2 = 1.5 MiB -> ends 6 MiB
        for (int b = 0; b < 8; ++b) {
            gemm_bt<64, 64, 0, 1><<<dim3(NN / 64, TWO_D / 64), dim3(256), 0, stream>>>(
                x, wuv, UVb, DD, TWO_D, b * NN, 0, nullptr, nullptr, nullptr, nullptr, flags);
            gather_max<<<dim3(NN / 8), dim3(DD), 0, stream>>>(
                UVb, idx + (size_t)b * NN * KNNK, bn1g, bn1b, bn1m, bn1v, Mbb, flags);
            gemm_bt<64, 64, 1, 0><<<dim3(NN / 64, DD / 64), dim3(256), 0, stream>>>(
                Mbb, w2b, d_out, DD, DD, 0, b * NN, bn2g, bn2b, bn2m, bn2v, flags);
        }
    }
}

// Round 7
// 211.901 us; speedup vs baseline: 3.2660x; 1.0857x over previous
//
#include <hip/hip_runtime.h>
#include <hip/hip_bf16.h>

#define NN 2048
#define DD 384
#define BNROWS 16384       // 8*2048
#define KNNK 8
#define TWO_D 768
#define EPSV 1e-5f
#define SLOPE 0.2f
#define LDT 72   // padded LDS stride (bf16 elems)

typedef __attribute__((ext_vector_type(8))) short short8;
typedef __attribute__((ext_vector_type(4))) float f32x4;
typedef __hip_bfloat16 bf16;

// load element i of p as float, where p is fp32 (isf32=1) or bf16 (isf32=0)
__device__ __forceinline__ float ldf(const void* p, long i, int isf32) {
    return isf32 ? ((const float*)p)[i]
                 : __bfloat162float(((const bf16*)p)[i]);
}

__device__ __forceinline__ short f2b(float x) {
    bf16 h = __float2bfloat16(x);
    short s;
    __builtin_memcpy(&s, &h, 2);
    return s;
}

// Branch-free sorted top-8 insert (desc values; strict > => ties keep earlier
// arrival above => smallest index wins given index-ascending scan).
// Invariant b0>=b1>=...>=b7 lets the value shift be a single med3:
//   b_s' = med3(b_{s-1}, nd, b_s). Index chain needs the compares.
// Updates descend so old b_{s-1}/i_{s-1} are used.
#define LADDER(nd, ci) { \
    bool c0 = (nd) > b0, c1 = (nd) > b1, c2 = (nd) > b2, c3 = (nd) > b3; \
    bool c4 = (nd) > b4, c5 = (nd) > b5, c6 = (nd) > b6, c7 = (nd) > b7; \
    i7 = c6 ? i6 : (c7 ? (ci) : i7); \
    i6 = c5 ? i5 : (c6 ? (ci) : i6); \
    i5 = c4 ? i4 : (c5 ? (ci) : i5); \
    i4 = c3 ? i3 : (c4 ? (ci) : i4); \
    i3 = c2 ? i2 : (c3 ? (ci) : i3); \
    i2 = c1 ? i1 : (c2 ? (ci) : i2); \
    i1 = c0 ? i0 : (c1 ? (ci) : i1); \
    i0 = c0 ? (ci) : i0; \
    b7 = __builtin_amdgcn_fmed3f(b6, (nd), b7); \
    b6 = __builtin_amdgcn_fmed3f(b5, (nd), b6); \
    b5 = __builtin_amdgcn_fmed3f(b4, (nd), b5); \
    b4 = __builtin_amdgcn_fmed3f(b3, (nd), b4); \
    b3 = __builtin_amdgcn_fmed3f(b2, (nd), b3); \
    b2 = __builtin_amdgcn_fmed3f(b1, (nd), b2); \
    b1 = __builtin_amdgcn_fmed3f(b0, (nd), b1); \
    b0 = fmaxf(b0, (nd)); \
}

#define DECL_STATE() \
    float b0 = -INFINITY, b1 = -INFINITY, b2 = -INFINITY, b3 = -INFINITY, \
          b4 = -INFINITY, b5 = -INFINITY, b6 = -INFINITY, b7 = -INFINITY; \
    int i0 = 0, i1 = 0, i2 = 0, i3 = 0, i4 = 0, i5 = 0, i6 = 0, i7 = 0;

// ---- dtype detection ----
// flags[0]=x fp32?  flags[1]=bn fp32?  flags[2]=center fp32?  flags[3]=w1 fp32?  flags[4]=w2 fp32?
__global__ void detect_flags(const void* x, const void* center, const void* w1,
                             const void* w2, const void* bng, int* flags) {
    __shared__ int sbad;
    int t = threadIdx.x;
    const unsigned short* p;
    if (blockIdx.x == 0)      p = (const unsigned short*)x;
    else if (blockIdx.x == 1) p = (const unsigned short*)center;
    else if (blockIdx.x == 2) p = (const unsigned short*)w1;
    else                      p = (const unsigned short*)w2;
    if (t == 0) sbad = 0;
    __syncthreads();
    int bad = 0;
    for (int i = t; i < 2048; i += 256) {
        unsigned e = (p[i] >> 7) & 0xFF;
        if (e >= 134) bad = 1;   // impossible for N(0,1) bf16; near-certain for fp32 bits
    }
    if (bad) atomicOr(&sbad, 1);
    __syncthreads();
    if (t == 0) {
        int fi = (blockIdx.x == 0) ? 0 : (blockIdx.x == 1) ? 2 : (blockIdx.x == 2) ? 3 : 4;
        flags[fi] = sbad ? 1 : 0;
        if (blockIdx.x == 0)
            flags[1] = (((const unsigned*)bng)[0] == 0x3F800000u) ? 1 : 0;
    }
}

// ---- merged weight prep: wuv rows 0..383 = w1a, 384..767 = w1b-w1a; w2->bf16
__global__ void prep_weights(const void* __restrict__ w1, const void* __restrict__ w2,
                             bf16* __restrict__ wuv, bf16* __restrict__ w2b,
                             const int* __restrict__ flags) {
    int t = blockIdx.x * 256 + threadIdx.x;
    if (t < TWO_D * DD) {
        int f = flags[3];
        int r = t / DD, c = t % DD;
        float o;
        if (r < DD) {
            o = ldf(w1, (long)r * TWO_D + c, f);
        } else {
            int rr = r - DD;
            o = ldf(w1, (long)rr * TWO_D + DD + c, f) - ldf(w1, (long)rr * TWO_D + c, f);
        }
        wuv[t] = __float2bfloat16(o);
    } else {
        int u = t - TWO_D * DD;
        if (u < DD * DD) {
            int f = flags[4];
            w2b[u] = __float2bfloat16(ldf(w2, u, f));
        }
    }
}

// ---- KNN phase 1 (path A): 16 chunks x 128 cand, stores (val,idx) transposed
__global__ void knn_p1a(const void* __restrict__ center, float* __restrict__ cval,
                        int* __restrict__ cidx, const int* __restrict__ flags) {
#pragma clang fp contract(off)
    int f = flags[2];
    __shared__ float4 cs[128];
    int t = threadIdx.x;
    int q = blockIdx.x * 256 + t;
    int cc = blockIdx.y;                 // candidate chunk 0..15
    int b = q >> 11;
    long cbase = (long)b * NN * 3;
    int n = q & (NN - 1);
    float qx = ldf(center, cbase + n * 3 + 0, f);
    float qy = ldf(center, cbase + n * 3 + 1, f);
    float qz = ldf(center, cbase + n * 3 + 2, f);
    float sqq = (qx * qx + qy * qy) + qz * qz;
    if (t < 128) {
        int cj = cc * 128 + t;
        float cx = ldf(center, cbase + cj * 3 + 0, f);
        float cy = ldf(center, cbase + cj * 3 + 1, f);
        float cz = ldf(center, cbase + cj * 3 + 2, f);
        cs[t] = make_float4(cx, cy, cz, (cx * cx + cy * cy) + cz * cz);
    }
    __syncthreads();
    DECL_STATE();
    int cbase2 = cc * 128;
    for (int u = 0; u < 128; ++u) {
        float4 c4v = cs[u];
        float dot = (qx * c4v.x + qy * c4v.y) + qz * c4v.z;
        float nd = (2.0f * dot - sqq) - c4v.w;
        int ci = cbase2 + u;
        LADDER(nd, ci);
    }
    size_t o = (size_t)(cc * KNNK) * BNROWS + q;
    cval[o + 0 * BNROWS] = b0; cidx[o + 0 * BNROWS] = i0;
    cval[o + 1 * BNROWS] = b1; cidx[o + 1 * BNROWS] = i1;
    cval[o + 2 * BNROWS] = b2; cidx[o + 2 * BNROWS] = i2;
    cval[o + 3 * BNROWS] = b3; cidx[o + 3 * BNROWS] = i3;
    cval[o + 4 * BNROWS] = b4; cidx[o + 4 * BNROWS] = i4;
    cval[o + 5 * BNROWS] = b5; cidx[o + 5 * BNROWS] = i5;
    cval[o + 6 * BNROWS] = b6; cidx[o + 6 * BNROWS] = i6;
    cval[o + 7 * BNROWS] = b7; cidx[o + 7 * BNROWS] = i7;
}

// ---- KNN phase 2 (path A): coalesced merge of 128 stored (val,idx) ----
__global__ void knn_p2a(const float* __restrict__ cval, const int* __restrict__ cidx,
                        int* __restrict__ idx_out) {
    int q = blockIdx.x * 64 + threadIdx.x;
    DECL_STATE();
    for (int e = 0; e < 128; ++e) {
        float nd = cval[(size_t)e * BNROWS + q];
        int ci = cidx[(size_t)e * BNROWS + q];
        LADDER(nd, ci);
    }
    idx_out[q * KNNK + 0] = i0; idx_out[q * KNNK + 1] = i1;
    idx_out[q * KNNK + 2] = i2; idx_out[q * KNNK + 3] = i3;
    idx_out[q * KNNK + 4] = i4; idx_out[q * KNNK + 5] = i5;
    idx_out[q * KNNK + 6] = i6; idx_out[q * KNNK + 7] = i7;
}

// ---- KNN phase 1 (path B, small ws): 8 chunks x 256, idx-only store ----
__global__ void knn_p1b(const void* __restrict__ center, int* __restrict__ cidx,
                        const int* __restrict__ flags) {
#pragma clang fp contract(off)
    int f = flags[2];
    __shared__ float4 cs[256];
    int t = threadIdx.x;
    int q = blockIdx.x * 256 + t;
    int cc = blockIdx.y;
    int b = q >> 11;
    long cbase = (long)b * NN * 3;
    int n = q & (NN - 1);
    float qx = ldf(center, cbase + n * 3 + 0, f);
    float qy = ldf(center, cbase + n * 3 + 1, f);
    float qz = ldf(center, cbase + n * 3 + 2, f);
    float sqq = (qx * qx + qy * qy) + qz * qz;
    {
        int cj = cc * 256 + t;
        float cx = ldf(center, cbase + cj * 3 + 0, f);
        float cy = ldf(center, cbase + cj * 3 + 1, f);
        float cz = ldf(center, cbase + cj * 3 + 2, f);
        cs[t] = make_float4(cx, cy, cz, (cx * cx + cy * cy) + cz * cz);
    }
    __syncthreads();
    DECL_STATE();
    int cbase2 = cc * 256;
    for (int u = 0; u < 256; ++u) {
        float4 c4v = cs[u];
        float dot = (qx * c4v.x + qy * c4v.y) + qz * c4v.z;
        float nd = (2.0f * dot - sqq) - c4v.w;
        int ci = cbase2 + u;
        LADDER(nd, ci);
    }
    size_t o = (size_t)(cc * KNNK) * BNROWS + q;
    cidx[o + 0 * BNROWS] = i0; cidx[o + 1 * BNROWS] = i1;
    cidx[o + 2 * BNROWS] = i2; cidx[o + 3 * BNROWS] = i3;
    cidx[o + 4 * BNROWS] = i4; cidx[o + 5 * BNROWS] = i5;
    cidx[o + 6 * BNROWS] = i6; cidx[o + 7 * BNROWS] = i7;
}

// ---- KNN phase 2 (path B): merge 64, recomputing exact distances ----
__global__ void knn_p2b(const void* __restrict__ center, const int* __restrict__ cidx,
                        int* __restrict__ idx_out, const int* __restrict__ flags) {
#pragma clang fp contract(off)
    int f = flags[2];
    int q = blockIdx.x * 64 + threadIdx.x;
    int b = q >> 11;
    long cbase = (long)b * NN * 3;
    int n = q & (NN - 1);
    float qx = ldf(center, cbase + n * 3 + 0, f);
    float qy = ldf(center, cbase + n * 3 + 1, f);
    float qz = ldf(center, cbase + n * 3 + 2, f);
    float sqq = (qx * qx + qy * qy) + qz * qz;
    DECL_STATE();
    for (int e = 0; e < 64; ++e) {
        int ci = cidx[(size_t)e * BNROWS + q];
        float cx = ldf(center, cbase + ci * 3 + 0, f);
        float cy = ldf(center, cbase + ci * 3 + 1, f);
        float cz = ldf(center, cbase + ci * 3 + 2, f);
        float cw = (cx * cx + cy * cy) + cz * cz;
        float dot = (qx * cx + qy * cy) + qz * cz;
        float nd = (2.0f * dot - sqq) - cw;
        LADDER(nd, ci);
    }
    idx_out[q * KNNK + 0] = i0; idx_out[q * KNNK + 1] = i1;
    idx_out[q * KNNK + 2] = i2; idx_out[q * KNNK + 3] = i3;
    idx_out[q * KNNK + 4] = i4; idx_out[q * KNNK + 5] = i5;
    idx_out[q * KNNK + 6] = i6; idx_out[q * KNNK + 7] = i7;
}

// ---- MFMA bf16 GEMM: C[crow0+M x Nout] = A[arow0+M x K] * Bw[Nout x K]^T ----
// AFP: 1 = A dtype from flags[0] (fp32 converted during staging), 0 = A bf16.
// MODE 0: plain bf16 store. MODE 1: BN+leaky epilogue, out dtype per flags[0].
template<int BM, int BN, int MODE, int AFP>
__global__ __launch_bounds__(256) void gemm_bt(
    const void* __restrict__ A, const bf16* __restrict__ Bw,
    void* __restrict__ Cv, int Kdim, int Nout, int arow0, int crow0,
    const void* __restrict__ g2, const void* __restrict__ b2,
    const void* __restrict__ m2, const void* __restrict__ v2,
    const int* __restrict__ flags) {
    constexpr int TI = BM / 32, TJ = BN / 32;
    __shared__ __align__(16) short As[BM * LDT];
    __shared__ __align__(16) short Bs[BN * LDT];
    int fa = AFP ? flags[0] : 0;
    int tid = threadIdx.x;
    int bm0 = blockIdx.x * BM;
    int bn0 = blockIdx.y * BN;
    int w = tid >> 6, lane = tid & 63;
    int quad = lane >> 4, lr = lane & 15;
    int wm = (w & 1) * (BM / 2), wn = (w >> 1) * (BN / 2);
    f32x4 acc[TI][TJ] = {};
    for (int k0 = 0; k0 < Kdim; k0 += 64) {
        __syncthreads();
#pragma unroll
        for (int c = 0; c < BM / 32; ++c) {
            int ci = tid + c * 256;
            int row = ci >> 3, col = (ci & 7) * 8;
            if (AFP && fa) {
                const float* Af = (const float*)A;
                const float4* p = (const float4*)&Af[(size_t)(arow0 + bm0 + row) * Kdim + k0 + col];
                float4 f0 = p[0], f1 = p[1];
                short8 v;
                v[0] = f2b(f0.x); v[1] = f2b(f0.y); v[2] = f2b(f0.z); v[3] = f2b(f0.w);
                v[4] = f2b(f1.x); v[5] = f2b(f1.y); v[6] = f2b(f1.z); v[7] = f2b(f1.w);
                *reinterpret_cast<short8*>(&As[row * LDT + col]) = v;
            } else {
                const bf16* Ab = (const bf16*)A;
                *reinterpret_cast<int4*>(&As[row * LDT + col]) =
                    *reinterpret_cast<const int4*>(&Ab[(size_t)(arow0 + bm0 + row) * Kdim + k0 + col]);
            }
        }
#pragma unroll
        for (int c = 0; c < BN / 32; ++c) {
            int ci = tid + c * 256;
            int row = ci >> 3, col = (ci & 7) * 8;
            *reinterpret_cast<int4*>(&Bs[row * LDT + col]) =
                *reinterpret_cast<const int4*>(&Bw[(size_t)(bn0 + row) * Kdim + k0 + col]);
        }
        __syncthreads();
#pragma unroll
        for (int s = 0; s < 2; ++s) {
            short8 af[TI], bfr[TJ];
#pragma unroll
            for (int i = 0; i < TI; ++i)
                af[i] = *reinterpret_cast<const short8*>(&As[(wm + i * 16 + lr) * LDT + s * 32 + quad * 8]);
#pragma unroll
            for (int j = 0; j < TJ; ++j)
                bfr[j] = *reinterpret_cast<const short8*>(&Bs[(wn + j * 16 + lr) * LDT + s * 32 + quad * 8]);
#pragma unroll
            for (int i = 0; i < TI; ++i)
#pragma unroll
                for (int j = 0; j < TJ; ++j)
                    acc[i][j] = __builtin_amdgcn_mfma_f32_16x16x32_bf16(af[i], bfr[j], acc[i][j], 0, 0, 0);
        }
    }
    if (MODE == 0) {
        bf16* Cb = (bf16*)Cv;
#pragma unroll
        for (int i = 0; i < TI; ++i)
#pragma unroll
            for (int j = 0; j < TJ; ++j) {
                int col = bn0 + wn + j * 16 + lr;
#pragma unroll
                for (int r = 0; r < 4; ++r) {
                    int row = crow0 + bm0 + wm + i * 16 + quad * 4 + r;
                    Cb[(size_t)row * Nout + col] = __float2bfloat16(acc[i][j][r]);
                }
            }
    } else {
        int fb = flags[1];
        int fo = flags[0];   // output dtype follows x's dtype
#pragma unroll
        for (int j = 0; j < TJ; ++j) {
            int col = bn0 + wn + j * 16 + lr;
            float g  = ldf(g2, col, fb);
            float be = ldf(b2, col, fb);
            float mu = ldf(m2, col, fb);
            float va = ldf(v2, col, fb);
            float sc = g / sqrtf(va + EPSV);
            float sh = be - mu * sc;
#pragma unroll
            for (int i = 0; i < TI; ++i) {
#pragma unroll
                for (int r = 0; r < 4; ++r) {
                    int row = crow0 + bm0 + wm + i * 16 + quad * 4 + r;
                    float vvv = acc[i][j][r] * sc + sh;
                    vvv = vvv >= 0.f ? vvv : SLOPE * vvv;
                    if (fo) ((float*)Cv)[(size_t)row * Nout + col] = vvv;
                    else    ((bf16*)Cv)[(size_t)row * Nout + col] = __float2bfloat16(vvv);
                }
            }
        }
    }
}

// ---- gather neighbors + BN1 + leaky + max over k ----
__global__ void gather_max(const bf16* __restrict__ UV, const int* __restrict__ idx,
                           const void* __restrict__ g1, const void* __restrict__ b1,
                           const void* __restrict__ m1, const void* __restrict__ v1,
                           bf16* __restrict__ Mout, const int* __restrict__ flags) {
    int fb = flags[1];
    int d = threadIdx.x;                 // 0..383
    int row0 = blockIdx.x * 8;
    float g  = ldf(g1, d, fb);
    float be = ldf(b1, d, fb);
    float mu = ldf(m1, d, fb);
    float va = ldf(v1, d, fb);
    float sc = g / sqrtf(va + EPSV);
    float sh = be - mu * sc;
    for (int rr = 0; rr < 8; ++rr) {
        int q = row0 + rr;
        int base = q & ~(NN - 1);
        float vv = __bfloat162float(UV[(size_t)q * TWO_D + DD + d]);
        float acc = -INFINITY;
#pragma unroll
        for (int k = 0; k < KNNK; ++k) {
            int nb = idx[q * KNNK + k];
            float u = __bfloat162float(UV[(size_t)(base + nb) * TWO_D + d]);
            float h = (u + vv) * sc + sh;
            h = h >= 0.f ? h : SLOPE * h;
            acc = fmaxf(acc, h);
        }
        Mout[(size_t)q * DD + d] = __float2bfloat16(acc);
    }
}

extern "C" void kernel_launch(void* const* d_in, const int* in_sizes, int n_in,
                              void* d_out, int out_size, void* d_ws, size_t ws_size,
                              hipStream_t stream) {
    const void* x      = d_in[0];
    const void* center = d_in[1];
    const void* w1     = d_in[2];
    const void* w2v    = d_in[3];
    const void* bn1g   = d_in[4];
    const void* bn1b   = d_in[5];
    const void* bn1m   = d_in[6];
    const void* bn1v   = d_in[7];
    const void* bn2g   = d_in[8];
    const void* bn2b   = d_in[9];
    const void* bn2m   = d_in[10];
    const void* bn2v   = d_in[11];

    char* ws = (char*)d_ws;
    // Persistent: idx [0,0x80000) | wuv [0x80000,0x110000) | flags [0x118000,+32)
    //             w2b [0x120000,+0x48000)
    int*  idx   = (int*)ws;
    bf16* wuv   = (bf16*)(ws + 0x80000);
    int*  flags = (int*)(ws + 0x118000);
    bf16* w2b   = (bf16*)(ws + 0x120000);

    detect_flags<<<dim3(4), dim3(256), 0, stream>>>(x, center, w1, w2v, bn1g, flags);
    prep_weights<<<dim3((TWO_D * DD + DD * DD + 255) / 256), dim3(256), 0, stream>>>(
        w1, w2v, wuv, w2b, flags);

    if (ws_size >= (48u << 20)) {
        // ---- Path A ----
        // Transient knn scratch overlaps UV's region (dead before gemm1 writes):
        // cval [8 MiB,16 MiB) | cidx [16 MiB,24 MiB). UV [8,32) MiB, Mb [32,44) MiB.
        float* cval = (float*)(ws + (8u << 20));
        int*   cidx = (int*)(ws + (16u << 20));
        bf16*  UV   = (bf16*)(ws + (8u << 20));
        bf16*  Mb   = (bf16*)(ws + (32u << 20));
        knn_p1a<<<dim3(BNROWS / 256, 16), dim3(256), 0, stream>>>(center, cval, cidx, flags);
        knn_p2a<<<dim3(BNROWS / 64), dim3(64), 0, stream>>>(cval, cidx, idx);
        gemm_bt<128, 128, 0, 1><<<dim3(BNROWS / 128, TWO_D / 128), dim3(256), 0, stream>>>(
            x, wuv, UV, DD, TWO_D, 0, 0, nullptr, nullptr, nullptr, nullptr, flags);
        gather_max<<<dim3(BNROWS / 8), dim3(DD), 0, stream>>>(
            UV, idx, bn1g, bn1b, bn1m, bn1v, Mb, flags);
        gemm_bt<128, 128, 1, 0><<<dim3(BNROWS / 128, DD / 128), dim3(256), 0, stream>>>(
            Mb, w2b, d_out, DD, DD, 0, 0, bn2g, bn2b, bn2m, bn2v, flags);
    } else {
        // ---- Path B: small ws (6 MiB). cidx 4 MiB at 0x180000 (transient,
        // overlapped by UVb/Mbb which are written only after knn_p2b). ----
        int*  cidx = (int*)(ws + 0x180000);
        bf16* UVb  = (bf16*)(ws + 0x180000);       // 2048*768*2 = 3 MiB
        bf16* Mbb  = (bf16*)(ws + 0x480000);       // 2048*384*2 = 1.5 MiB -> ends 6 MiB
        knn_p1b<<<dim3(BNROWS / 256, 8), dim3(256), 0, stream>>>(center, cidx, flags);
        knn_p2b<<<dim3(BNROWS / 64), dim3(64), 0, stream>>>(center, cidx, idx, flags);
        for (int b = 0; b < 8; ++b) {
            gemm_bt<64, 64, 0, 1><<<dim3(NN / 64, TWO_D / 64), dim3(256), 0, stream>>>(
                x, wuv, UVb, DD, TWO_D, b * NN, 0, nullptr, nullptr, nullptr, nullptr, flags);
            gather_max<<<dim3(NN / 8), dim3(DD), 0, stream>>>(
                UVb, idx + (size_t)b * NN * KNNK, bn1g, bn1b, bn1m, bn1v, Mbb, flags);
            gemm_bt<64, 64, 1, 0><<<dim3(NN / 64, DD / 64), dim3(256), 0, stream>>>(
                Mbb, w2b, d_out, DD, DD, 0, b * NN, bn2g, bn2b, bn2m, bn2v, flags);
        }
    }
}